// Round 5
// baseline (137.727 us; speedup 1.0000x reference)
//
#include <hip/hip_runtime.h>
#include <hip/hip_bf16.h>
#include <stdint.h>

// Problem dims (fixed by reference setup_inputs)
#define BQ   8192   // query rows
#define DIM  1024   // feature dim
#define NK   2048   // number of keys/values

typedef unsigned short u16;
using f32x4  = __attribute__((ext_vector_type(4))) float;
using bf16x8 = __attribute__((ext_vector_type(8))) __bf16;
using u16x4  = __attribute__((ext_vector_type(4))) unsigned short;

// ---------- helpers ----------

__device__ __forceinline__ u16 f2bf(float f) {
    uint32_t u = __float_as_uint(f);
    u += 0x7FFFu + ((u >> 16) & 1u);
    return (u16)(u >> 16);
}

__device__ __forceinline__ void gload_lds16(const void* g, void* l) {
    __builtin_amdgcn_global_load_lds(
        (const __attribute__((address_space(1))) void*)g,
        (__attribute__((address_space(3))) void*)l,
        16, 0, 0);
}

__device__ __forceinline__ f32x4 mfma16(bf16x8 a, bf16x8 b, f32x4 c) {
    return __builtin_amdgcn_mfma_f32_16x16x32_bf16(a, b, c, 0, 0, 0);
}

template<int N>
__device__ __forceinline__ void vmcnt_wait() {
    if constexpr (N == 0)      asm volatile("s_waitcnt vmcnt(0)" ::: "memory");
    else if constexpr (N == 4) asm volatile("s_waitcnt vmcnt(4)" ::: "memory");
    else if constexpr (N == 6) asm volatile("s_waitcnt vmcnt(6)" ::: "memory");
}

// ---------- stage 0: fp32 -> bf16 convert ----------

__global__ void cvt_f32_bf16(const float* __restrict__ in, u16* __restrict__ out, int n4) {
    int i = blockIdx.x * blockDim.x + threadIdx.x;
    if (i < n4) {
        f32x4 v = reinterpret_cast<const f32x4*>(in)[i];
        u16x4 o;
        o.x = f2bf(v[0]); o.y = f2bf(v[1]); o.z = f2bf(v[2]); o.w = f2bf(v[3]);
        reinterpret_cast<u16x4*>(out)[i] = o;
    }
}

// transpose V (NK x DIM fp32) -> VT (DIM x NK bf16)
__global__ void transpose_cvt(const float* __restrict__ V, u16* __restrict__ VT) {
    __shared__ float tile[32][33];
    int d0 = blockIdx.x * 32;
    int n0 = blockIdx.y * 32;
    int tx = threadIdx.x, ty = threadIdx.y;
#pragma unroll
    for (int i = 0; i < 4; ++i)
        tile[ty + i * 8][tx] = V[(size_t)(n0 + ty + i * 8) * DIM + d0 + tx];
    __syncthreads();
#pragma unroll
    for (int i = 0; i < 4; ++i)
        VT[(size_t)(d0 + ty + i * 8) * NK + n0 + tx] = f2bf(tile[tx][ty + i * 8]);
}

// ---------- 2-phase deep-pipelined GEMM: C = scale * A[M,K] * B[N,K]^T ----------
// BM=256, BN in {256,128}. 8 waves (2M x 4N), BK=64.
// Per K-tile: P1 = {stage A-hi(t+1)->nb; ds A-lo,B-lo,B-hi; 32(16) MFMA m0-3 x all-n}
//             barrier
//             P2 = {stage A-lo,B-lo,B-hi(t+2)->cb; ds A-hi; 32(16) MFMA m4-7 x all-n}
//             vmcnt(NS) [loads aged >= 1 full K-tile; 3 half-tiles stay in flight]
//             barrier
// Only 2 barriers / K-tile, one counted vmcnt, setprio around MFMA clusters,
// T2 XOR-swizzled LDS, XCD block swizzle. Grid must be 256 blocks (nbn == 8).

template<int BN>
__global__ __launch_bounds__(512, 2)
void gemm2p(const u16* __restrict__ A, const u16* __restrict__ B, float* __restrict__ C,
            int K, int lda, int ldb, int ldc, float scale) {
    constexpr int HB   = BN / 2;          // rows per B half-tile (128 or 64)
    constexpr int NREP = BN / 64;         // n-frags per wave (4 or 2)
    constexpr int NH   = NREP / 2;        // n-frags per half (2 or 1)
    constexpr int AC   = 2;               // gload instrs per A half-tile (per thread)
    constexpr int BC   = (BN == 256) ? 2 : 1;
    constexpr int NS   = AC + 2 * BC;     // in-flight allowance: 6 / 4

    __shared__ u16 Al[2][2][128 * 64];    // [dbuf][half][row*64]
    __shared__ u16 Bl[2][2][HB * 64];

    const int tid  = threadIdx.x;
    const int wave = tid >> 6;
    const int lane = tid & 63;
    const int wr = wave >> 2;             // 0..1 (M)
    const int wc = wave & 3;              // 0..3 (N)

    // XCD-aware bijective swizzle; nbn == 8 hardcoded
    int id = blockIdx.x;
    const int cpx = gridDim.x >> 3;
    id = (id & 7) * cpx + (id >> 3);
    const int bm = id >> 3;
    const int bn = id & 7;

    // ---- staging geometry: one call = 64 rows x 128B; wave w covers rows w*8..w*8+7
    const int lsub  = lane >> 3;
    const int lslot = lane & 7;
    const int srcCol = ((lslot ^ lsub) << 3);   // inverse-swizzled k offset (elements)

    const u16* aG = A + (size_t)(bm * 256 + wave * 8 + lsub) * lda + srcCol;
    const u16* bG = B + (size_t)(bn * BN  + wave * 8 + lsub) * ldb + srcCol;
    const int ldsChunk = (wave * 8) * 64;       // u16 offset of this wave's 1KB slice

    auto STAGE_A = [&](int buf, int h, int kt) {
#pragma unroll
        for (int c = 0; c < AC; ++c)
            gload_lds16(aG + (size_t)(h * 128 + c * 64) * lda + (size_t)kt * 64,
                        &Al[buf][h][c * 64 * 64 + ldsChunk]);
    };
    auto STAGE_B = [&](int buf, int h, int kt) {
#pragma unroll
        for (int c = 0; c < BC; ++c)
            gload_lds16(bG + (size_t)(h * HB + c * 64) * ldb + (size_t)kt * 64,
                        &Bl[buf][h][c * 64 * 64 + ldsChunk]);
    };

    // ---- swizzled fragment reads (row stride 128B; byte ^= (row&7)<<4)
    const int fr = lane & 15;
    const int cXor = (((lane >> 4) << 4) ^ ((lane & 7) << 4));
    auto LDA = [&](int buf, int h, int mi, int kk) -> bf16x8 {   // mi 0..3 within half
        int off = (wr * 64 + mi * 16 + fr) * 128 + (cXor ^ (kk << 6));
        return *reinterpret_cast<const bf16x8*>(
            reinterpret_cast<const char*>(&Al[buf][h][0]) + off);
    };
    auto LDB = [&](int buf, int h, int ni, int kk) -> bf16x8 {   // ni 0..NH-1 within half
        int r = (BN == 256 ? wc * 32 + ni * 16 : wc * 16) + fr;
        int off = r * 128 + (cXor ^ (kk << 6));
        return *reinterpret_cast<const bf16x8*>(
            reinterpret_cast<const char*>(&Bl[buf][h][0]) + off);
    };

    f32x4 acc[8][NREP] = {};
    const int NT = K >> 6;                // 16 or 32 here (NT >= 2)

    // ---- prologue: tile 0 fully + tile 1 minus A-hi; wait tile 0 ready
    STAGE_A(0, 0, 0); STAGE_A(0, 1, 0); STAGE_B(0, 0, 0); STAGE_B(0, 1, 0);
    STAGE_A(1, 0, 1); STAGE_B(1, 0, 1); STAGE_B(1, 1, 1);
    vmcnt_wait<NS>();                     // tile-0 halves (oldest) complete
    __builtin_amdgcn_s_barrier();

    for (int t = 0; t < NT; ++t) {
        const int cb = t & 1, nb = cb ^ 1;
        bf16x8 af[4][2], bflo[NH][2], bfhi[NH][2];

        // ===== P1: stage A-hi(t+1)->nb; ds A-lo,B-lo,B-hi; MFMA m0-3 x all n =====
        if (t + 1 < NT) STAGE_A(nb, 1, t + 1);
#pragma unroll
        for (int mi = 0; mi < 4; ++mi) { af[mi][0] = LDA(cb, 0, mi, 0); af[mi][1] = LDA(cb, 0, mi, 1); }
#pragma unroll
        for (int ni = 0; ni < NH; ++ni) {
            bflo[ni][0] = LDB(cb, 0, ni, 0); bflo[ni][1] = LDB(cb, 0, ni, 1);
            bfhi[ni][0] = LDB(cb, 1, ni, 0); bfhi[ni][1] = LDB(cb, 1, ni, 1);
        }
        __builtin_amdgcn_s_setprio(1);
#pragma unroll
        for (int mi = 0; mi < 4; ++mi)
#pragma unroll
            for (int ni = 0; ni < NH; ++ni) {
                acc[mi][ni] = mfma16(af[mi][0], bflo[ni][0], acc[mi][ni]);
                acc[mi][ni] = mfma16(af[mi][1], bflo[ni][1], acc[mi][ni]);
                acc[mi][NH + ni] = mfma16(af[mi][0], bfhi[ni][0], acc[mi][NH + ni]);
                acc[mi][NH + ni] = mfma16(af[mi][1], bfhi[ni][1], acc[mi][NH + ni]);
            }
        __builtin_amdgcn_s_setprio(0);
        __builtin_amdgcn_s_barrier();   // cb's A-lo,B-lo,B-hi reads complete

        // ===== P2: stage A-lo,B-lo,B-hi(t+2)->cb; ds A-hi; MFMA m4-7 x all n =====
        if (t + 2 < NT) { STAGE_A(cb, 0, t + 2); STAGE_B(cb, 0, t + 2); STAGE_B(cb, 1, t + 2); }
#pragma unroll
        for (int mi = 0; mi < 4; ++mi) { af[mi][0] = LDA(cb, 1, mi, 0); af[mi][1] = LDA(cb, 1, mi, 1); }
        __builtin_amdgcn_s_setprio(1);
#pragma unroll
        for (int mi = 0; mi < 4; ++mi)
#pragma unroll
            for (int ni = 0; ni < NH; ++ni) {
                acc[4 + mi][ni] = mfma16(af[mi][0], bflo[ni][0], acc[4 + mi][ni]);
                acc[4 + mi][ni] = mfma16(af[mi][1], bflo[ni][1], acc[4 + mi][ni]);
                acc[4 + mi][NH + ni] = mfma16(af[mi][0], bfhi[ni][0], acc[4 + mi][NH + ni]);
                acc[4 + mi][NH + ni] = mfma16(af[mi][1], bfhi[ni][1], acc[4 + mi][NH + ni]);
            }
        __builtin_amdgcn_s_setprio(0);
        // one counted wait per K-tile: gates ALL of tile t+1 (aged >= 1 full tile)
        if (t + 2 < NT)      vmcnt_wait<NS>();
        else if (t + 1 < NT) vmcnt_wait<0>();
        __builtin_amdgcn_s_barrier();   // publish tile t+1
    }

    // ---- epilogue: C/D layout col = lane&15, row = (lane>>4)*4 + j
    const int jrow = ((lane >> 4) << 2);
#pragma unroll
    for (int m = 0; m < 8; ++m) {
        int gr = bm * 256 + (m < 4 ? 0 : 128) + wr * 64 + (m & 3) * 16 + jrow;
#pragma unroll
        for (int j = 0; j < 4; ++j) {
            float* cp = C + (size_t)(gr + j) * ldc;
#pragma unroll
            for (int n = 0; n < NREP; ++n) {
                int gc = bn * BN + (n < NH ? 0 : HB)
                       + (BN == 256 ? wc * 32 : wc * 16) + (n % NH) * 16 + fr;
                cp[gc] = acc[m][n][j] * scale;
            }
        }
    }
}

// ---------- stage 2: row softmax1 + 16-step sigmoid long-division reciprocal ----------

__global__ void softmax_recip(const float* __restrict__ S, u16* __restrict__ W) {
    const int row  = blockIdx.x;
    const int t    = threadIdx.x;
    const int wid  = t >> 6;
    const int lane = t & 63;

    const float* s = S + (size_t)row * NK;
    f32x4 v0 = reinterpret_cast<const f32x4*>(s)[t];
    f32x4 v1 = reinterpret_cast<const f32x4*>(s)[256 + t];

    float m = fmaxf(fmaxf(fmaxf(v0[0], v0[1]), fmaxf(v0[2], v0[3])),
                    fmaxf(fmaxf(v1[0], v1[1]), fmaxf(v1[2], v1[3])));
#pragma unroll
    for (int off = 32; off; off >>= 1) m = fmaxf(m, __shfl_xor(m, off));

    __shared__ float redm[4];
    __shared__ float reds[4];
    if (lane == 0) redm[wid] = m;
    __syncthreads();
    m = fmaxf(fmaxf(redm[0], redm[1]), fmaxf(redm[2], redm[3]));

    float e[8];
    e[0] = expf(v0[0] - m); e[1] = expf(v0[1] - m);
    e[2] = expf(v0[2] - m); e[3] = expf(v0[3] - m);
    e[4] = expf(v1[0] - m); e[5] = expf(v1[1] - m);
    e[6] = expf(v1[2] - m); e[7] = expf(v1[3] - m);
    float sum = e[0] + e[1] + e[2] + e[3] + e[4] + e[5] + e[6] + e[7];
#pragma unroll
    for (int off = 32; off; off >>= 1) sum += __shfl_xor(sum, off);
    if (lane == 0) reds[wid] = sum;
    __syncthreads();
    sum = reds[0] + reds[1] + reds[2] + reds[3];

    const float d = 1.0f + sum;

    float r = 1.0f, q = 0.0f, w = 0.5f;
#pragma unroll
    for (int i = 0; i < 16; ++i) {
        float doubled = 2.0f * r;
        float st = 1.0f / (1.0f + expf(-100.0f * (doubled - d)));
        r = doubled - d * st;
        q += w * st;
        w *= 0.5f;
    }

    u16x4 o0, o1;
    o0.x = f2bf(e[0] * q); o0.y = f2bf(e[1] * q); o0.z = f2bf(e[2] * q); o0.w = f2bf(e[3] * q);
    o1.x = f2bf(e[4] * q); o1.y = f2bf(e[5] * q); o1.z = f2bf(e[6] * q); o1.w = f2bf(e[7] * q);
    u16x4* wp = reinterpret_cast<u16x4*>(W + (size_t)row * NK);
    wp[t]       = o0;
    wp[256 + t] = o1;
}

// ---------- launch ----------

extern "C" void kernel_launch(void* const* d_in, const int* in_sizes, int n_in,
                              void* d_out, int out_size, void* d_ws, size_t ws_size,
                              hipStream_t stream) {
    const float* Q = (const float*)d_in[0];
    const float* K = (const float*)d_in[1];
    const float* V = (const float*)d_in[2];
    float* out = (float*)d_out;

    char* ws = (char*)d_ws;
    u16*   Qb  = (u16*)(ws);
    u16*   Kb  = (u16*)(ws + (16u << 20));
    u16*   VbT = (u16*)(ws + (20u << 20));
    float* S   = (float*)(ws + (24u << 20));
    u16*   W   = (u16*)(ws + (88u << 20));

    {
        int n4 = BQ * DIM / 4;
        cvt_f32_bf16<<<(n4 + 255) / 256, 256, 0, stream>>>(Q, Qb, n4);
    }
    {
        int n4 = NK * DIM / 4;
        cvt_f32_bf16<<<(n4 + 255) / 256, 256, 0, stream>>>(K, Kb, n4);
    }
    transpose_cvt<<<dim3(DIM / 32, NK / 32), dim3(32, 8), 0, stream>>>(V, VbT);

    // stage 1: S = (1/32) * Qb @ Kb^T   (M=8192, N=2048, K=1024) — 32x8 = 256 blocks
    gemm2p<256><<<(BQ / 256) * (NK / 256), 512, 0, stream>>>(
        Qb, Kb, S, DIM, DIM, DIM, NK, 0.03125f);

    // stage 2: softmax1 + reciprocal scan -> W bf16
    softmax_recip<<<BQ, 256, 0, stream>>>(S, W);

    // stage 3: out = W @ VbT^T          (M=8192, N=1024, K=2048) — 32x8 = 256 blocks
    gemm2p<128><<<(BQ / 256) * (DIM / 128), 512, 0, stream>>>(
        W, VbT, out, NK, NK, NK, DIM, 1.0f);
}

// Round 6
// 111.550 us; speedup vs baseline: 1.2347x; 1.2347x over previous
//
#include <hip/hip_runtime.h>
#include <hip/hip_bf16.h>
#include <stdint.h>

// Problem dims (fixed by reference setup_inputs)
#define BQ   8192   // query rows
#define DIM  1024   // feature dim
#define NK   2048   // number of keys/values

typedef unsigned short u16;
using f32x4  = __attribute__((ext_vector_type(4))) float;
using bf16x8 = __attribute__((ext_vector_type(8))) __bf16;
using f16x8  = __attribute__((ext_vector_type(8))) _Float16;
using u16x4  = __attribute__((ext_vector_type(4))) unsigned short;
using u16x8  = __attribute__((ext_vector_type(8))) unsigned short;

// ---------- helpers ----------

__device__ __forceinline__ u16 f2bf(float f) {
    // round-to-nearest-even fp32 -> bf16
    uint32_t u = __float_as_uint(f);
    u += 0x7FFFu + ((u >> 16) & 1u);
    return (u16)(u >> 16);
}

__device__ __forceinline__ u16 f2h(float f) {
    _Float16 h = (_Float16)f;             // v_cvt_f16_f32 (RTN)
    return __builtin_bit_cast(unsigned short, h);
}

__device__ __forceinline__ void gload_lds16(const void* g, void* l) {
    __builtin_amdgcn_global_load_lds(
        (const __attribute__((address_space(1))) void*)g,
        (__attribute__((address_space(3))) void*)l,
        16, 0, 0);
}

template<bool F16>
__device__ __forceinline__ f32x4 mfmaT(u16x8 a, u16x8 b, f32x4 c) {
    if constexpr (F16)
        return __builtin_amdgcn_mfma_f32_16x16x32_f16(
            __builtin_bit_cast(f16x8, a), __builtin_bit_cast(f16x8, b), c, 0, 0, 0);
    else
        return __builtin_amdgcn_mfma_f32_16x16x32_bf16(
            __builtin_bit_cast(bf16x8, a), __builtin_bit_cast(bf16x8, b), c, 0, 0, 0);
}

// ---------- stage 0: fp32 -> bf16 convert ----------

__global__ void cvt_f32_bf16(const float* __restrict__ in, u16* __restrict__ out, int n4) {
    int i = blockIdx.x * blockDim.x + threadIdx.x;
    if (i < n4) {
        f32x4 v = reinterpret_cast<const f32x4*>(in)[i];
        u16x4 o;
        o.x = f2bf(v[0]); o.y = f2bf(v[1]); o.z = f2bf(v[2]); o.w = f2bf(v[3]);
        reinterpret_cast<u16x4*>(out)[i] = o;
    }
}

// transpose V (NK x DIM fp32) -> VT (DIM x NK fp16)
__global__ void transpose_cvt(const float* __restrict__ V, u16* __restrict__ VT) {
    __shared__ float tile[32][33];
    int d0 = blockIdx.x * 32;
    int n0 = blockIdx.y * 32;
    int tx = threadIdx.x, ty = threadIdx.y;
#pragma unroll
    for (int i = 0; i < 4; ++i)
        tile[ty + i * 8][tx] = V[(size_t)(n0 + ty + i * 8) * DIM + d0 + tx];
    __syncthreads();
#pragma unroll
    for (int i = 0; i < 4; ++i)
        VT[(size_t)(d0 + ty + i * 8) * NK + n0 + tx] = f2h(tile[tx][ty + i * 8]);
}

// ---------- GEMM (round-2 best structure): C[M,N] = scale * A[M,K]*B[N,K]^T ----------
// BM=256, BN in {256,128}. 8 waves (2M x 4N), wave tile 128 x BN/4, BK=64,
// double-buffered LDS, stage for t+1 issued at top of iter t (drained by the
// tile-boundary __syncthreads after 4 MFMA phases), T2 XOR-swizzled LDS
// (inverse-swizzled global source + swizzled ds_read), setprio around MFMA
// clusters, bijective XCD block swizzle. F16 selects fp16-input MFMA (else bf16).

template<int BN, bool F16, typename OT>
__global__ __launch_bounds__(512, 2)
void gemm256(const u16* __restrict__ A, const u16* __restrict__ B, OT* __restrict__ C,
             int K, int lda, int ldb, int ldc, float scale, int nbn) {
    constexpr int WTN  = BN / 4;    // per-wave N span (64 or 32)
    constexpr int NREP = BN / 64;   // N fragments per wave (4 or 2)
    constexpr int NH   = NREP / 2;  // frags per N-half (2 or 1)
    constexpr int BCALLS = (BN == 256) ? 4 : 2;

    __shared__ u16 As[2][256 * 64];
    __shared__ u16 Bs[2][BN * 64];

    const int tid  = threadIdx.x;
    const int wave = tid >> 6;
    const int lane = tid & 63;
    const int wr = wave >> 2;       // 0..1
    const int wc = wave & 3;        // 0..3

    // XCD-aware bijective swizzle (grid is a multiple of 8)
    int id = blockIdx.x;
    const int cpx = gridDim.x >> 3;
    id = (id & 7) * cpx + (id >> 3);
    const int bm = id / nbn;
    const int bn = id % nbn;

    // ---- staging geometry (each gload call: 8 rows x 128B = 1 KiB) ----
    const int lsub  = lane >> 3;                 // row within 8-row chunk
    const int lslot = lane & 7;                  // 16B slot within 128B row
    const int srcColEl = ((lslot ^ lsub) << 3);  // inverse-swizzled k offset (elements)

    const int aRow0 = wr * 128 + wc * 32;        // wave's A chunk rows (+c*8)
    int bRow0;
    if constexpr (BN == 256) bRow0 = (wc >> 1) * 128 + (wr * 2 + (wc & 1)) * 32;
    else                     bRow0 = wave * 16;

    const u16* aSrc = A + (size_t)(bm * 256 + aRow0 + lsub) * lda + srcColEl;
    const u16* bSrc = B + (size_t)(bn * BN  + bRow0 + lsub) * ldb + srcColEl;

    f32x4 acc[8][NREP] = {};

    const int NT = K >> 6;

    auto STAGE = [&](int buf, int kt) {
        const size_t ko = (size_t)kt * 64;
#pragma unroll
        for (int c2 = 0; c2 < 4; ++c2)
            gload_lds16(aSrc + (size_t)c2 * 8 * lda + ko, &As[buf][(aRow0 + c2 * 8) * 64]);
#pragma unroll
        for (int c2 = 0; c2 < BCALLS; ++c2)
            gload_lds16(bSrc + (size_t)c2 * 8 * ldb + ko, &Bs[buf][(bRow0 + c2 * 8) * 64]);
    };

    // swizzled fragment loads (row stride 128B; byte ^= (row&7)<<4)
    auto LDA_frag = [&](const char* base, int m, int kk) -> u16x8 {
        int r   = wr * 128 + m * 16 + (lane & 15);
        int off = r * 128 + (((kk * 64) + ((lane >> 4) << 4)) ^ ((lane & 7) << 4));
        return *reinterpret_cast<const u16x8*>(base + off);
    };
    auto LDB_frag = [&](const char* base, int n, int kk) -> u16x8 {
        int r   = wc * WTN + n * 16 + (lane & 15);
        int off = r * 128 + (((kk * 64) + ((lane >> 4) << 4)) ^ ((lane & 7) << 4));
        return *reinterpret_cast<const u16x8*>(base + off);
    };

    STAGE(0, 0);
    __syncthreads();          // drain prologue stage; tile 0 published

    int cbuf = 0;
    for (int t = 0; t < NT; ++t) {
        if (t + 1 < NT) STAGE(cbuf ^ 1, t + 1);   // aged across this tile's 4 phases
        __builtin_amdgcn_sched_barrier(0);

        const char* aB = (const char*)&As[cbuf][0];
        const char* bB = (const char*)&Bs[cbuf][0];

        u16x8 af[4][2];
        u16x8 bf0[NH][2], bf1[NH][2];

        // ---- phase 0: A(mh=0) + B(nh=0), MFMA Q(0,0) ----
#pragma unroll
        for (int mi = 0; mi < 4; ++mi) { af[mi][0] = LDA_frag(aB, mi, 0); af[mi][1] = LDA_frag(aB, mi, 1); }
#pragma unroll
        for (int ni = 0; ni < NH; ++ni) { bf0[ni][0] = LDB_frag(bB, ni, 0); bf0[ni][1] = LDB_frag(bB, ni, 1); }
        __builtin_amdgcn_s_setprio(1);
#pragma unroll
        for (int mi = 0; mi < 4; ++mi)
#pragma unroll
            for (int ni = 0; ni < NH; ++ni) {
                acc[mi][ni] = mfmaT<F16>(af[mi][0], bf0[ni][0], acc[mi][ni]);
                acc[mi][ni] = mfmaT<F16>(af[mi][1], bf0[ni][1], acc[mi][ni]);
            }
        __builtin_amdgcn_s_setprio(0);

        // ---- phase 1: B(nh=1), MFMA Q(0,1) ----
#pragma unroll
        for (int ni = 0; ni < NH; ++ni) { bf1[ni][0] = LDB_frag(bB, NH + ni, 0); bf1[ni][1] = LDB_frag(bB, NH + ni, 1); }
        __builtin_amdgcn_s_setprio(1);
#pragma unroll
        for (int mi = 0; mi < 4; ++mi)
#pragma unroll
            for (int ni = 0; ni < NH; ++ni) {
                acc[mi][NH + ni] = mfmaT<F16>(af[mi][0], bf1[ni][0], acc[mi][NH + ni]);
                acc[mi][NH + ni] = mfmaT<F16>(af[mi][1], bf1[ni][1], acc[mi][NH + ni]);
            }
        __builtin_amdgcn_s_setprio(0);

        // ---- phase 2: A(mh=1), MFMA Q(1,1) ----
#pragma unroll
        for (int mi = 0; mi < 4; ++mi) { af[mi][0] = LDA_frag(aB, 4 + mi, 0); af[mi][1] = LDA_frag(aB, 4 + mi, 1); }
        __builtin_amdgcn_s_setprio(1);
#pragma unroll
        for (int mi = 0; mi < 4; ++mi)
#pragma unroll
            for (int ni = 0; ni < NH; ++ni) {
                acc[4 + mi][NH + ni] = mfmaT<F16>(af[mi][0], bf1[ni][0], acc[4 + mi][NH + ni]);
                acc[4 + mi][NH + ni] = mfmaT<F16>(af[mi][1], bf1[ni][1], acc[4 + mi][NH + ni]);
            }
        __builtin_amdgcn_s_setprio(0);

        // ---- phase 3: MFMA Q(1,0) (reuses bf0) ----
        __builtin_amdgcn_s_setprio(1);
#pragma unroll
        for (int mi = 0; mi < 4; ++mi)
#pragma unroll
            for (int ni = 0; ni < NH; ++ni) {
                acc[4 + mi][ni] = mfmaT<F16>(af[mi][0], bf0[ni][0], acc[4 + mi][ni]);
                acc[4 + mi][ni] = mfmaT<F16>(af[mi][1], bf0[ni][1], acc[4 + mi][ni]);
            }
        __builtin_amdgcn_s_setprio(0);

        __syncthreads();      // drains (aged) stage of t+1 + publishes it; frees cbuf
        cbuf ^= 1;
    }

    // epilogue: C/D layout col = lane&15, row = (lane>>4)*4 + j
    const int col0 = bn * BN + wc * WTN + (lane & 15);
    const int row0 = bm * 256 + wr * 128 + ((lane >> 4) << 2);
#pragma unroll
    for (int m = 0; m < 8; ++m) {
#pragma unroll
        for (int j = 0; j < 4; ++j) {
            int row = row0 + m * 16 + j;
            OT* cp = C + (size_t)row * ldc + col0;
#pragma unroll
            for (int n = 0; n < NREP; ++n)
                cp[n * 16] = (OT)(acc[m][n][j] * scale);
        }
    }
}

// ---------- stage 2: wave-per-row softmax1 + 16-step sigmoid long-division ----------
// S fp16 (BQ x NK) -> W fp16 (BQ x NK). 4 waves/block = 4 rows/block, no LDS.

__global__ __launch_bounds__(256)
void softmax_recip_f16(const u16* __restrict__ S, u16* __restrict__ W) {
    const int lane = threadIdx.x & 63;
    const int row  = blockIdx.x * 4 + (threadIdx.x >> 6);

    const u16x8* sp = reinterpret_cast<const u16x8*>(S + (size_t)row * NK);
    u16x8 raw[4];
#pragma unroll
    for (int j = 0; j < 4; ++j) raw[j] = sp[lane + j * 64];   // coalesced 16B/lane

    float e[32];
    float mx = -1e30f;
#pragma unroll
    for (int j = 0; j < 4; ++j)
#pragma unroll
        for (int i = 0; i < 8; ++i) {
            float f = (float)__builtin_bit_cast(_Float16, (unsigned short)raw[j][i]);
            e[j * 8 + i] = f;
            mx = fmaxf(mx, f);
        }
#pragma unroll
    for (int off = 32; off; off >>= 1) mx = fmaxf(mx, __shfl_xor(mx, off));

    float sum = 0.f;
#pragma unroll
    for (int i = 0; i < 32; ++i) { e[i] = expf(e[i] - mx); sum += e[i]; }
#pragma unroll
    for (int off = 32; off; off >>= 1) sum += __shfl_xor(sum, off);

    const float d = 1.0f + sum;

    // non-restoring long division, 16 bits, soft comparator sigmoid(100*(2r - d))
    float r = 1.0f, q = 0.0f, w = 0.5f;
#pragma unroll
    for (int i = 0; i < 16; ++i) {
        float doubled = 2.0f * r;
        float st = 1.0f / (1.0f + expf(-100.0f * (doubled - d)));
        r = doubled - d * st;
        q += w * st;
        w *= 0.5f;
    }

    u16x8* wp = reinterpret_cast<u16x8*>(W + (size_t)row * NK);
#pragma unroll
    for (int j = 0; j < 4; ++j) {
        u16x8 o;
#pragma unroll
        for (int i = 0; i < 8; ++i) o[i] = f2h(e[j * 8 + i] * q);
        wp[lane + j * 64] = o;
    }
}

// ---------- launch ----------

extern "C" void kernel_launch(void* const* d_in, const int* in_sizes, int n_in,
                              void* d_out, int out_size, void* d_ws, size_t ws_size,
                              hipStream_t stream) {
    const float* Q = (const float*)d_in[0];
    const float* K = (const float*)d_in[1];
    const float* V = (const float*)d_in[2];
    float* out = (float*)d_out;

    char* ws = (char*)d_ws;
    // ws layout (bytes):
    //   Qb  bf16 8192x1024 : 16 MiB
    //   Kb  bf16 2048x1024 :  4 MiB
    //   VhT fp16 1024x2048 :  4 MiB
    //   S   fp16 8192x2048 : 32 MiB
    //   W   fp16 8192x2048 : 32 MiB   -> total 88 MiB
    u16* Qb  = (u16*)(ws);
    u16* Kb  = (u16*)(ws + (16u << 20));
    u16* VhT = (u16*)(ws + (20u << 20));
    u16* S   = (u16*)(ws + (24u << 20));
    u16* W   = (u16*)(ws + (56u << 20));

    {
        int n4 = BQ * DIM / 4;
        cvt_f32_bf16<<<(n4 + 255) / 256, 256, 0, stream>>>(Q, Qb, n4);
    }
    {
        int n4 = NK * DIM / 4;
        cvt_f32_bf16<<<(n4 + 255) / 256, 256, 0, stream>>>(K, Kb, n4);
    }
    transpose_cvt<<<dim3(DIM / 32, NK / 32), dim3(32, 8), 0, stream>>>(V, VhT);

    // stage 1: S(fp16) = (1/32) * Qb @ Kb^T   (M=8192, N=2048, K=1024) — 256 blocks
    gemm256<256, false, _Float16><<<(BQ / 256) * (NK / 256), 512, 0, stream>>>(
        Qb, Kb, (_Float16*)S, DIM, DIM, DIM, NK, 0.03125f, NK / 256);

    // stage 2: softmax1 + reciprocal scan -> W fp16 (wave per row)
    softmax_recip_f16<<<BQ / 4, 256, 0, stream>>>(S, W);

    // stage 3: out = W @ VhT^T (f16 MFMA)     (M=8192, N=1024, K=2048) — 256 blocks
    gemm256<128, true, float><<<(BQ / 256) * (DIM / 128), 512, 0, stream>>>(
        W, VhT, out, NK, NK, NK, DIM, 1.0f, DIM / 128);
}